// Round 3
// baseline (358.189 us; speedup 1.0000x reference)
//
#include <hip/hip_runtime.h>
#include <hip/hip_bf16.h>
#include <hip/hip_cooperative_groups.h>

namespace cg = cooperative_groups;

#define N 8192
#define THREADS 256
#define GRID 512
#define KCHUNKS 8
#define KCHUNK (N / KCHUNKS)   // 1024
#define BK 512
#define YSTR 520               // padded LDS stride (bf16 elements)
#define PSTR 520               // padded LDS stride (floats)

typedef __attribute__((ext_vector_type(8))) short short8;
typedef __attribute__((ext_vector_type(4))) float floatx4;
typedef __attribute__((ext_vector_type(2))) float f32x2;
typedef __attribute__((ext_vector_type(4))) unsigned int uint32x4;

struct f32x2x2 { f32x2 lo, hi; };

// ---- workspace byte offsets (total ~11.2 MB) ----
#define POST_OFF  0u           // float[8*N]: x,y,z,r2,-2x,-2y,-2z    262144
#define Y1T_OFF   262144u      // bf16[32*N]                           524288
#define Y2T_OFF   786432u      // bf16[8*N]                            131072
#define CNTT_OFF  917504u      // float[N]                              32768
#define PC_OFF    950272u      // float[8*N]                           262144
#define P1_OFF    1212416u     // float[8*N*32]                       8388608
#define P2_OFF    9601024u     // float[8*N*8]                        2097152

__device__ __forceinline__ f32x2 pk_fma(f32x2 a, f32x2 b, f32x2 c) {
    f32x2 d; asm("v_pk_fma_f32 %0, %1, %2, %3" : "=v"(d) : "v"(a), "v"(b), "v"(c)); return d;
}

#define LD2(P) __builtin_bit_cast(f32x2x2, *(const float4*)(P))

// k-side rows pre-scaled: X=-2x_k, Y=-2y_k, Z=-2z_k, R=r_k^2
// t = r_k^2 - 2*dot(p_m,p_k);  t < 6.25 - r_m^2  <=>  d^2 < 6.25
#define MASK2(XP, YP, ZP, RP, PRXV, PRYV, PRZV, THR, OUT) { \
    f32x2 _t = pk_fma((XP), (PRXV), (RP)); \
    _t = pk_fma((YP), (PRYV), _t); \
    _t = pk_fma((ZP), (PRZV), _t); \
    (OUT) = (_t.x < (THR) ? 0x3F80u : 0u) | (_t.y < (THR) ? 0x3F800000u : 0u); }

#define MASK8(OUT, XA, XB, YA, YB, ZA, ZB, RA, RB, PRXV, PRYV, PRZV, THR) { \
    uint32x4 _u; \
    MASK2(XA.lo, YA.lo, ZA.lo, RA.lo, PRXV, PRYV, PRZV, THR, _u[0]) \
    MASK2(XA.hi, YA.hi, ZA.hi, RA.hi, PRXV, PRYV, PRZV, THR, _u[1]) \
    MASK2(XB.lo, YB.lo, ZB.lo, RB.lo, PRXV, PRYV, PRZV, THR, _u[2]) \
    MASK2(XB.hi, YB.hi, ZB.hi, RB.hi, PRXV, PRYV, PRZV, THR, _u[3]) \
    (OUT) = __builtin_bit_cast(short8, _u); }

// shared-memory union: phases reuse the same 41.6 KB block
union SMem {
    struct {
        float sB[48], sEmb[104], sW1[1280], sb1[32];
        float xfs[16][41];
        unsigned short sT[32 * 24];     // stride 24: 16B-aligned uint4 readback
    } prep;
    struct { unsigned short sY[32 * YSTR]; float sPos[4 * PSTR]; } a1;   // 41600 B
    struct { unsigned short sY[9 * YSTR];  float sPos[4 * PSTR]; } a2;
    struct { float sW2[256], sb2[8], sCnt[16]; unsigned short sT[8 * 24]; } m2;
};

// ---------------- phase: prep (512 blocks x 16 rows, 8 threads/row) ----------------
__device__ __forceinline__ void phase_prep(int bid, int tid, SMem& sm,
    const float* __restrict__ lpf, const float* __restrict__ Bm,
    const float* __restrict__ emb, const float* __restrict__ W1,
    const float* __restrict__ b1, char* __restrict__ ws)
{
    auto& P = sm.prep;
    for (int i = tid; i < 48;   i += THREADS) P.sB[i]   = Bm[i];
    for (int i = tid; i < 104;  i += THREADS) P.sEmb[i] = emb[i];
    for (int i = tid; i < 1280; i += THREADS) P.sW1[i]  = W1[i];
    for (int i = tid; i < 32;   i += THREADS) P.sb1[i]  = b1[i];
    __syncthreads();

    const int base = bid * 16;
    const int row_local = tid >> 3;            // 0..31 (only 0..15 active)
    const int fslice    = tid & 7;
    float px = 0.f, py = 0.f, pz = 0.f;

    if (row_local < 16) {
        const int row = base + row_local;
        const float4 lp = ((const float4*)lpf)[row];
        px = lp.x; py = lp.y; pz = lp.z;
        int fi = (int)lp.w;
        fi = fi < 0 ? 0 : (fi > 12 ? 12 : fi);
        const float r2 = px * px + py * py + pz * pz;
        float* posT = (float*)(ws + POST_OFF);
        if (fslice < 7) {
            const float v = (fslice == 0) ? px
                          : (fslice == 1) ? py
                          : (fslice == 2) ? pz
                          : (fslice == 3) ? r2
                          : (fslice == 4) ? -2.0f * px
                          : (fslice == 5) ? -2.0f * py
                          :                 -2.0f * pz;
            posT[(size_t)fslice * N + row] = v;
        }
        const float TWO_PI = 6.283185307179586f;
        #pragma unroll
        for (int t = 0; t < 2; ++t) {
            const int k = fslice * 2 + t;      // 0..15
            const float pr = (px * P.sB[k] + py * P.sB[16 + k] + pz * P.sB[32 + k]) * TWO_PI;
            P.xfs[row_local][k]      = sinf(pr);
            P.xfs[row_local][16 + k] = cosf(pr);
        }
        P.xfs[row_local][32 + fslice] = P.sEmb[fi * 8 + fslice];
    }
    __syncthreads();

    if (row_local < 16) {
        float acc[4];
        #pragma unroll
        for (int j = 0; j < 4; ++j) acc[j] = P.sb1[fslice * 4 + j];
        #pragma unroll
        for (int f = 0; f < 40; ++f) {
            const float xv = P.xfs[row_local][f];
            #pragma unroll
            for (int j = 0; j < 4; ++j)
                acc[j] += xv * P.sW1[f * 32 + fslice * 4 + j];
        }
        __hip_bfloat16* sT = (__hip_bfloat16*)P.sT;
        #pragma unroll
        for (int j = 0; j < 4; ++j)
            sT[(fslice * 4 + j) * 24 + row_local] = __float2bfloat16(acc[j]);
    }
    __syncthreads();

    if (tid < 64) {
        const int feat = tid >> 1, half = tid & 1;
        unsigned short* y1t = (unsigned short*)(ws + Y1T_OFF);
        *(uint4*)(y1t + (size_t)feat * N + base + half * 8) =
            *(const uint4*)&P.sT[feat * 24 + half * 8];
    }
}

// ---------------- phase: agg1 (bid -> rowblk 0..63, kc 0..7) ----------------
__device__ __forceinline__ void phase_agg1(int bid, int tid, SMem& sm, char* __restrict__ ws)
{
    auto& A = sm.a1;
    const float* posT = (const float*)(ws + POST_OFF);
    const unsigned short* y1t = (const unsigned short*)(ws + Y1T_OFF);
    float* part1 = (float*)(ws + P1_OFF);
    float* pcnt  = (float*)(ws + PC_OFF);

    const int lane = tid & 63;
    const int wv   = tid >> 6;
    const int quad = lane >> 4;
    const int ncol = lane & 15;
    const int rowblk = bid & 63, kc = bid >> 6;
    const int rowbase = rowblk * 128;
    const int kcbase  = kc * KCHUNK;

    const int m0 = rowbase + wv * 32 + ncol;
    const int m1 = m0 + 16;
    const float prx0 = posT[m0], pry0 = posT[N + m0], prz0 = posT[2 * N + m0];
    const float thr0 = 6.25f - posT[3 * N + m0];
    const float prx1 = posT[m1], pry1 = posT[N + m1], prz1 = posT[2 * N + m1];
    const float thr1 = 6.25f - posT[3 * N + m1];

    const f32x2 prx0v = {prx0, prx0}, pry0v = {pry0, pry0}, prz0v = {prz0, prz0};
    const f32x2 prx1v = {prx1, prx1}, pry1v = {pry1, pry1}, prz1v = {prz1, prz1};

    short8 bones;
    #pragma unroll
    for (int j = 0; j < 8; ++j) bones[j] = (ncol == 0) ? (short)0x3F80 : (short)0;

    floatx4 acc[2][2], accc[2];
    #pragma unroll
    for (int t = 0; t < 2; ++t) {
        acc[t][0] = (floatx4){0.f,0.f,0.f,0.f};
        acc[t][1] = (floatx4){0.f,0.f,0.f,0.f};
        accc[t]   = (floatx4){0.f,0.f,0.f,0.f};
    }

    const int c32 = tid & 31, r8 = tid >> 5;
    for (int kb = 0; kb < KCHUNK; kb += BK) {
        const int kg = kcbase + kb;
        __syncthreads();
        #pragma unroll
        for (int rr = 0; rr < 4; ++rr) {
            const int r = r8 + rr * 8;
            #pragma unroll
            for (int cc = 0; cc < 2; ++cc)
                *(uint4*)&A.sY[r * YSTR + cc * 256 + c32 * 8] =
                    *(const uint4*)(y1t + (size_t)r * N + kg + cc * 256 + c32 * 8);
        }
        {   // stage k-side rows: -2x,-2y,-2z,r2  (posT rows 4,5,6,3)
            const int dim = tid >> 6, i = tid & 63;
            const int srow = (dim == 3) ? 3 : 4 + dim;
            #pragma unroll
            for (int cc = 0; cc < 2; ++cc)
                *(float4*)&A.sPos[dim * PSTR + cc * 256 + i * 4] =
                    *(const float4*)(posT + (size_t)srow * N + kg + cc * 256 + i * 4);
        }
        __syncthreads();

        #pragma unroll 4
        for (int kt = 0; kt < BK; kt += 32) {
            const int koff = kt + quad * 8;
            const f32x2x2 xA = LD2(&A.sPos[koff]),            xB = LD2(&A.sPos[koff + 4]);
            const f32x2x2 yA = LD2(&A.sPos[PSTR + koff]),     yB = LD2(&A.sPos[PSTR + koff + 4]);
            const f32x2x2 zA = LD2(&A.sPos[2 * PSTR + koff]), zB = LD2(&A.sPos[2 * PSTR + koff + 4]);
            const f32x2x2 rA = LD2(&A.sPos[3 * PSTR + koff]), rB = LD2(&A.sPos[3 * PSTR + koff + 4]);

            short8 af0, af1;
            MASK8(af0, xA, xB, yA, yB, zA, zB, rA, rB, prx0v, pry0v, prz0v, thr0)
            MASK8(af1, xA, xB, yA, yB, zA, zB, rA, rB, prx1v, pry1v, prz1v, thr1)

            const short8 b0 = *(const short8*)&A.sY[(ncol)      * YSTR + koff];
            const short8 b1 = *(const short8*)&A.sY[(16 + ncol) * YSTR + koff];

            acc[0][0] = __builtin_amdgcn_mfma_f32_16x16x32_bf16(af0, b0, acc[0][0], 0, 0, 0);
            acc[0][1] = __builtin_amdgcn_mfma_f32_16x16x32_bf16(af0, b1, acc[0][1], 0, 0, 0);
            accc[0]   = __builtin_amdgcn_mfma_f32_16x16x32_bf16(af0, bones, accc[0], 0, 0, 0);
            acc[1][0] = __builtin_amdgcn_mfma_f32_16x16x32_bf16(af1, b0, acc[1][0], 0, 0, 0);
            acc[1][1] = __builtin_amdgcn_mfma_f32_16x16x32_bf16(af1, b1, acc[1][1], 0, 0, 0);
            accc[1]   = __builtin_amdgcn_mfma_f32_16x16x32_bf16(af1, bones, accc[1], 0, 0, 0);
        }
    }

    float* p1 = part1 + (size_t)kc * N * 32;
    float* pc = pcnt  + (size_t)kc * N;
    #pragma unroll
    for (int t = 0; t < 2; ++t) {
        const int orow0 = rowbase + wv * 32 + t * 16 + quad * 4;
        #pragma unroll
        for (int r = 0; r < 4; ++r) {
            const int orow = orow0 + r;
            p1[(size_t)orow * 32 + ncol]      = acc[t][0][r];
            p1[(size_t)orow * 32 + 16 + ncol] = acc[t][1][r];
            if (ncol == 0) pc[orow] = accc[t][r];
        }
    }
}

// ---------------- phase: mlp2 (512 blocks x 16 rows, 8 threads/row) ----------------
__device__ __forceinline__ void phase_mlp2(int bid, int tid, SMem& sm,
    const float* __restrict__ W2, const float* __restrict__ b2, char* __restrict__ ws)
{
    auto& M = sm.m2;
    for (int i = tid; i < 256; i += THREADS) M.sW2[i] = W2[i];
    if (tid < 8) M.sb2[tid] = b2[tid];

    const int base = bid * 16;
    const int rl = tid >> 3;          // 0..31 (0..15 active)
    const int cs = tid & 7;
    const bool act = rl < 16;
    const float* part1 = (const float*)(ws + P1_OFF);
    const float* pcnt  = (const float*)(ws + PC_OFF);

    float4 s = make_float4(0.f, 0.f, 0.f, 0.f);
    if (act) {
        const int row = base + rl;
        #pragma unroll
        for (int kc = 0; kc < KCHUNKS; ++kc) {
            const float4 v = *(const float4*)(part1 + ((size_t)kc * N + row) * 32 + cs * 4);
            s.x += v.x; s.y += v.y; s.z += v.z; s.w += v.w;
        }
        if (cs == 0) {
            float cv = 0.f;
            #pragma unroll
            for (int kc = 0; kc < KCHUNKS; ++kc) cv += pcnt[(size_t)kc * N + row];
            M.sCnt[rl] = cv;
            ((float*)(ws + CNTT_OFF))[row] = cv;
        }
    }
    __syncthreads();

    if (act) {
        const float inv = 1.0f / (M.sCnt[rl] + 1e-6f);
        const float h0 = fmaxf(s.x * inv, 0.f), h1 = fmaxf(s.y * inv, 0.f),
                    h2 = fmaxf(s.z * inv, 0.f), h3 = fmaxf(s.w * inv, 0.f);
        float o[8];
        const int c = cs * 4;
        #pragma unroll
        for (int j = 0; j < 8; ++j)
            o[j] = h0 * M.sW2[c * 8 + j] + h1 * M.sW2[(c + 1) * 8 + j]
                 + h2 * M.sW2[(c + 2) * 8 + j] + h3 * M.sW2[(c + 3) * 8 + j];
        #pragma unroll
        for (int m = 1; m < 8; m <<= 1) {
            #pragma unroll
            for (int j = 0; j < 8; ++j) o[j] += __shfl_xor(o[j], m, 64);
        }
        if (cs == 0) {
            __hip_bfloat16* sT = (__hip_bfloat16*)M.sT;
            #pragma unroll
            for (int j = 0; j < 8; ++j)
                sT[j * 24 + rl] = __float2bfloat16(o[j] + M.sb2[j]);
        }
    }
    __syncthreads();

    if (tid < 16) {
        const int j = tid >> 1, half = tid & 1;
        unsigned short* y2t = (unsigned short*)(ws + Y2T_OFF);
        *(uint4*)(y2t + (size_t)j * N + base + half * 8) = *(const uint4*)&M.sT[j * 24 + half * 8];
    }
}

// ---------------- phase: agg2 (bid -> rowblk 0..63, kc 0..7) ----------------
__device__ __forceinline__ void phase_agg2(int bid, int tid, SMem& sm, char* __restrict__ ws)
{
    auto& A = sm.a2;
    const float* posT = (const float*)(ws + POST_OFF);
    const unsigned short* y2t = (const unsigned short*)(ws + Y2T_OFF);
    float* part2 = (float*)(ws + P2_OFF);

    const int lane = tid & 63;
    const int wv   = tid >> 6;
    const int quad = lane >> 4;
    const int ncol = lane & 15;
    const int rowblk = bid & 63, kc = bid >> 6;
    const int rowbase = rowblk * 128;
    const int kcbase  = kc * KCHUNK;

    // zero row 8 (read by lanes with ncol >= 8)
    for (int i = tid; i < 64; i += THREADS) {
        const uint4 z = {0u, 0u, 0u, 0u};
        *(uint4*)&A.sY[8 * YSTR + i * 8] = z;
    }

    const int m0 = rowbase + wv * 32 + ncol;
    const int m1 = m0 + 16;
    const float prx0 = posT[m0], pry0 = posT[N + m0], prz0 = posT[2 * N + m0];
    const float thr0 = 6.25f - posT[3 * N + m0];
    const float prx1 = posT[m1], pry1 = posT[N + m1], prz1 = posT[2 * N + m1];
    const float thr1 = 6.25f - posT[3 * N + m1];

    const f32x2 prx0v = {prx0, prx0}, pry0v = {pry0, pry0}, prz0v = {prz0, prz0};
    const f32x2 prx1v = {prx1, prx1}, pry1v = {pry1, pry1}, prz1v = {prz1, prz1};

    const int brow = (ncol < 8) ? ncol : 8;

    floatx4 acc[2];
    acc[0] = (floatx4){0.f,0.f,0.f,0.f};
    acc[1] = (floatx4){0.f,0.f,0.f,0.f};

    const int c32 = tid & 31, r8 = tid >> 5;
    for (int kb = 0; kb < KCHUNK; kb += BK) {
        const int kg = kcbase + kb;
        __syncthreads();
        #pragma unroll
        for (int cc = 0; cc < 2; ++cc)
            *(uint4*)&A.sY[r8 * YSTR + cc * 256 + c32 * 8] =
                *(const uint4*)(y2t + (size_t)r8 * N + kg + cc * 256 + c32 * 8);
        {
            const int dim = tid >> 6, i = tid & 63;
            const int srow = (dim == 3) ? 3 : 4 + dim;
            #pragma unroll
            for (int cc = 0; cc < 2; ++cc)
                *(float4*)&A.sPos[dim * PSTR + cc * 256 + i * 4] =
                    *(const float4*)(posT + (size_t)srow * N + kg + cc * 256 + i * 4);
        }
        __syncthreads();

        #pragma unroll 4
        for (int kt = 0; kt < BK; kt += 32) {
            const int koff = kt + quad * 8;
            const f32x2x2 xA = LD2(&A.sPos[koff]),            xB = LD2(&A.sPos[koff + 4]);
            const f32x2x2 yA = LD2(&A.sPos[PSTR + koff]),     yB = LD2(&A.sPos[PSTR + koff + 4]);
            const f32x2x2 zA = LD2(&A.sPos[2 * PSTR + koff]), zB = LD2(&A.sPos[2 * PSTR + koff + 4]);
            const f32x2x2 rA = LD2(&A.sPos[3 * PSTR + koff]), rB = LD2(&A.sPos[3 * PSTR + koff + 4]);

            short8 af0, af1;
            MASK8(af0, xA, xB, yA, yB, zA, zB, rA, rB, prx0v, pry0v, prz0v, thr0)
            MASK8(af1, xA, xB, yA, yB, zA, zB, rA, rB, prx1v, pry1v, prz1v, thr1)

            const short8 b0 = *(const short8*)&A.sY[brow * YSTR + koff];
            acc[0] = __builtin_amdgcn_mfma_f32_16x16x32_bf16(af0, b0, acc[0], 0, 0, 0);
            acc[1] = __builtin_amdgcn_mfma_f32_16x16x32_bf16(af1, b0, acc[1], 0, 0, 0);
        }
    }

    float* p2 = part2 + (size_t)kc * N * 8;
    #pragma unroll
    for (int t = 0; t < 2; ++t) {
        const int orow0 = rowbase + wv * 32 + t * 16 + quad * 4;
        #pragma unroll
        for (int r = 0; r < 4; ++r) {
            if (ncol < 8) {
                const int orow = orow0 + r;
                p2[(size_t)orow * 8 + ncol] = acc[t][r];
            }
        }
    }
}

// ---------------- phase: out (512 blocks x 16 rows, 16 threads/row) ----------------
__device__ __forceinline__ void phase_out(int bid, int tid, char* __restrict__ ws,
                                          float* __restrict__ out)
{
    const int rl  = tid >> 4;          // 0..15
    const int sub = tid & 15;
    const int cgp = sub >> 1;          // chunk 0..7
    const int half = sub & 1;          // col half
    const int row = bid * 16 + rl;
    const float* part2 = (const float*)(ws + P2_OFF);

    const float4 v = *(const float4*)(part2 + ((size_t)cgp * N + row) * 8 + half * 4);
    float s0 = v.x, s1 = v.y, s2 = v.z, s3 = v.w;
    #pragma unroll
    for (int m = 2; m <= 8; m <<= 1) {
        s0 += __shfl_xor(s0, m, 64); s1 += __shfl_xor(s1, m, 64);
        s2 += __shfl_xor(s2, m, 64); s3 += __shfl_xor(s3, m, 64);
    }
    if (cgp == 0) {
        const float cv  = ((const float*)(ws + CNTT_OFF))[row];
        const float inv = 1.0f / (cv + 1e-6f);
        *(float4*)(out + (size_t)row * 8 + half * 4) =
            make_float4(fmaxf(s0 * inv, 0.f), fmaxf(s1 * inv, 0.f),
                        fmaxf(s2 * inv, 0.f), fmaxf(s3 * inv, 0.f));
    }
}

// ---------------- fused cooperative kernel ----------------
__global__ __launch_bounds__(256, 2) void k_fused(
    const float* __restrict__ lpf, const float* __restrict__ Bm,
    const float* __restrict__ emb, const float* __restrict__ W1,
    const float* __restrict__ b1,  const float* __restrict__ W2,
    const float* __restrict__ b2,  char* __restrict__ ws,
    float* __restrict__ out)
{
    __shared__ SMem sm;
    cg::grid_group grid = cg::this_grid();
    const int bid = blockIdx.x, tid = threadIdx.x;

    phase_prep(bid, tid, sm, lpf, Bm, emb, W1, b1, ws);
    grid.sync();
    phase_agg1(bid, tid, sm, ws);
    grid.sync();
    phase_mlp2(bid, tid, sm, W2, b2, ws);
    grid.sync();
    phase_agg2(bid, tid, sm, ws);
    grid.sync();
    phase_out(bid, tid, ws, out);
}

// ---------------- standalone fallback kernels ----------------
__global__ __launch_bounds__(256) void k_prep_s(
    const float* __restrict__ lpf, const float* __restrict__ Bm,
    const float* __restrict__ emb, const float* __restrict__ W1,
    const float* __restrict__ b1, char* __restrict__ ws)
{ __shared__ SMem sm; phase_prep(blockIdx.x, threadIdx.x, sm, lpf, Bm, emb, W1, b1, ws); }

__global__ __launch_bounds__(256, 2) void k_agg1_s(char* __restrict__ ws)
{ __shared__ SMem sm; phase_agg1(blockIdx.x, threadIdx.x, sm, ws); }

__global__ __launch_bounds__(256) void k_mlp2_s(
    const float* __restrict__ W2, const float* __restrict__ b2, char* __restrict__ ws)
{ __shared__ SMem sm; phase_mlp2(blockIdx.x, threadIdx.x, sm, W2, b2, ws); }

__global__ __launch_bounds__(256, 2) void k_agg2_s(char* __restrict__ ws)
{ __shared__ SMem sm; phase_agg2(blockIdx.x, threadIdx.x, sm, ws); }

__global__ __launch_bounds__(256) void k_out_s(char* __restrict__ ws, float* __restrict__ out)
{ phase_out(blockIdx.x, threadIdx.x, ws, out); }

extern "C" void kernel_launch(void* const* d_in, const int* in_sizes, int n_in,
                              void* d_out, int out_size, void* d_ws, size_t ws_size,
                              hipStream_t stream) {
    (void)in_sizes; (void)n_in; (void)out_size; (void)ws_size;
    char* ws = (char*)d_ws;
    const float* lpf = (const float*)d_in[0];
    const float* B   = (const float*)d_in[1];
    const float* emb = (const float*)d_in[2];
    const float* W1  = (const float*)d_in[3];
    const float* b1  = (const float*)d_in[4];
    const float* W2  = (const float*)d_in[5];
    const float* b2  = (const float*)d_in[6];
    float* out = (float*)d_out;

    void* args[] = { (void*)&lpf, (void*)&B, (void*)&emb, (void*)&W1, (void*)&b1,
                     (void*)&W2, (void*)&b2, (void*)&ws, (void*)&out };
    hipError_t e = hipLaunchCooperativeKernel((void*)k_fused, dim3(GRID), dim3(THREADS),
                                              args, 0, stream);
    if (e != hipSuccess) {
        (void)hipGetLastError();   // clear sticky error, fall back to 5-launch path
        k_prep_s<<<GRID, THREADS, 0, stream>>>(lpf, B, emb, W1, b1, ws);
        k_agg1_s<<<GRID, THREADS, 0, stream>>>(ws);
        k_mlp2_s<<<GRID, THREADS, 0, stream>>>(W2, b2, ws);
        k_agg2_s<<<GRID, THREADS, 0, stream>>>(ws);
        k_out_s <<<GRID, THREADS, 0, stream>>>(ws, out);
    }
}

// Round 4
// 147.017 us; speedup vs baseline: 2.4364x; 2.4364x over previous
//
#include <hip/hip_runtime.h>
#include <hip/hip_bf16.h>

#define N 8192
#define THREADS 256
#define KCHUNKS 8
#define KCHUNK (N / KCHUNKS)   // 1024
#define BK 512
#define YSTR 520               // padded LDS stride (bf16 elements)

typedef __attribute__((ext_vector_type(8))) short short8;
typedef __attribute__((ext_vector_type(4))) float floatx4;
typedef __attribute__((ext_vector_type(2))) float f32x2;
typedef __attribute__((ext_vector_type(4))) unsigned int uint32x4;

struct f32x2x2 { f32x2 lo, hi; };

// ---- workspace byte offsets (total ~11.7 MB) ----
#define POST_OFF  0u           // float[8*N]: x,y,z,r2,-2x,-2y,-2z    262144
#define Y1T_OFF   262144u      // bf16[32*N]                           524288
#define Y2T_OFF   786432u      // bf16[8*N]                            131072
#define CNTT_OFF  917504u      // float[N]                              32768
#define PC_OFF    950272u      // float[8*N]                           262144
#define P1_OFF    1212416u     // float[8*N*32]                       8388608
#define P2_OFF    9601024u     // float[8*N*8]                        2097152

__device__ __forceinline__ f32x2 pk_fma(f32x2 a, f32x2 b, f32x2 c) {
    f32x2 d; asm("v_pk_fma_f32 %0, %1, %2, %3" : "=v"(d) : "v"(a), "v"(b), "v"(c)); return d;
}

#define LD2G(P) __builtin_bit_cast(f32x2x2, *(const float4*)(P))

// k-side rows pre-scaled: X=-2x_k, Y=-2y_k, Z=-2z_k, R=r_k^2
// t = r_k^2 - 2*dot(p_m,p_k);  t < 6.25 - r_m^2  <=>  d^2 < 6.25
#define MASK2(XP, YP, ZP, RP, PRXV, PRYV, PRZV, THR, OUT) { \
    f32x2 _t = pk_fma((XP), (PRXV), (RP)); \
    _t = pk_fma((YP), (PRYV), _t); \
    _t = pk_fma((ZP), (PRZV), _t); \
    (OUT) = (_t.x < (THR) ? 0x3F80u : 0u) | (_t.y < (THR) ? 0x3F800000u : 0u); }

#define MASK8(OUT, XA, XB, YA, YB, ZA, ZB, RA, RB, PRXV, PRYV, PRZV, THR) { \
    uint32x4 _u; \
    MASK2(XA.lo, YA.lo, ZA.lo, RA.lo, PRXV, PRYV, PRZV, THR, _u[0]) \
    MASK2(XA.hi, YA.hi, ZA.hi, RA.hi, PRXV, PRYV, PRZV, THR, _u[1]) \
    MASK2(XB.lo, YB.lo, ZB.lo, RB.lo, PRXV, PRYV, PRZV, THR, _u[2]) \
    MASK2(XB.hi, YB.hi, ZB.hi, RB.hi, PRXV, PRYV, PRZV, THR, _u[3]) \
    (OUT) = __builtin_bit_cast(short8, _u); }

// ---------------- prep: 256 blocks x 32 rows, 8 threads/row ----------------
__global__ __launch_bounds__(256) void k_prep(
    const float* __restrict__ lpf,    // (N,4) float32
    const float* __restrict__ Bm,     // (3,16)
    const float* __restrict__ emb,    // (13,8)
    const float* __restrict__ W1,     // (40,32)
    const float* __restrict__ b1,     // (32,)
    char* __restrict__ ws)
{
    __shared__ float sB[48], sEmb[104], sW1[1280], sb1[32];
    __shared__ float xfs[32][41];
    __shared__ __hip_bfloat16 sT[32 * 36];

    const int tid = threadIdx.x;
    for (int i = tid; i < 48;   i += THREADS) sB[i]   = Bm[i];
    for (int i = tid; i < 104;  i += THREADS) sEmb[i] = emb[i];
    for (int i = tid; i < 1280; i += THREADS) sW1[i]  = W1[i];
    for (int i = tid; i < 32;   i += THREADS) sb1[i]  = b1[i];
    __syncthreads();

    const int row_local = tid >> 3;            // 0..31
    const int fslice    = tid & 7;             // 0..7
    const int base = blockIdx.x * 32;
    const int row  = base + row_local;

    const float4 lp = ((const float4*)lpf)[row];
    const float px = lp.x, py = lp.y, pz = lp.z;
    int fi = (int)lp.w;
    fi = fi < 0 ? 0 : (fi > 12 ? 12 : fi);
    const float r2 = px * px + py * py + pz * pz;
    float* posT = (float*)(ws + POST_OFF);
    if (fslice < 7) {
        const float v = (fslice == 0) ? px
                      : (fslice == 1) ? py
                      : (fslice == 2) ? pz
                      : (fslice == 3) ? r2
                      : (fslice == 4) ? -2.0f * px
                      : (fslice == 5) ? -2.0f * py
                      :                 -2.0f * pz;
        posT[(size_t)fslice * N + row] = v;
    }

    const float TWO_PI = 6.283185307179586f;
    #pragma unroll
    for (int t = 0; t < 2; ++t) {
        const int k = fslice * 2 + t;          // 0..15
        const float pr = (px * sB[k] + py * sB[16 + k] + pz * sB[32 + k]) * TWO_PI;
        xfs[row_local][k]      = sinf(pr);
        xfs[row_local][16 + k] = cosf(pr);
    }
    xfs[row_local][32 + fslice] = sEmb[fi * 8 + fslice];
    __syncthreads();

    float acc[4];
    #pragma unroll
    for (int j = 0; j < 4; ++j) acc[j] = sb1[fslice * 4 + j];
    #pragma unroll
    for (int f = 0; f < 40; ++f) {
        const float xv = xfs[row_local][f];
        #pragma unroll
        for (int j = 0; j < 4; ++j)
            acc[j] += xv * sW1[f * 32 + fslice * 4 + j];
    }
    #pragma unroll
    for (int j = 0; j < 4; ++j)
        sT[(fslice * 4 + j) * 36 + row_local] = __float2bfloat16(acc[j]);
    __syncthreads();

    __hip_bfloat16* y1t = (__hip_bfloat16*)(ws + Y1T_OFF);
    if (tid < 128) {
        const int feat = tid >> 2, chunk = tid & 3;
        *(uint4*)(y1t + (size_t)feat * N + base + chunk * 8) = *(const uint4*)&sT[feat * 36 + chunk * 8];
    }
}

// ---------------- agg1: 64-row blocks, grid (128,8), pos from global, BK=512 ----------------
__global__ __launch_bounds__(256, 4) void k_agg1(char* __restrict__ ws)
{
    __shared__ __hip_bfloat16 sY[32 * YSTR];   // 33.3 KB (only LDS use)

    const float* posT = (const float*)(ws + POST_OFF);
    const __hip_bfloat16* y1t = (const __hip_bfloat16*)(ws + Y1T_OFF);
    float* part1 = (float*)(ws + P1_OFF);
    float* pcnt  = (float*)(ws + PC_OFF);

    const int tid  = threadIdx.x;
    const int lane = tid & 63;
    const int wv   = tid >> 6;        // wave 0..3
    const int quad = lane >> 4;       // 0..3
    const int ncol = lane & 15;
    const int rowbase = blockIdx.x * 64;
    const int kcbase  = blockIdx.y * KCHUNK;

    const int m0 = rowbase + wv * 16 + ncol;
    const float prx0 = posT[m0], pry0 = posT[N + m0], prz0 = posT[2 * N + m0];
    const float thr0 = 6.25f - posT[3 * N + m0];

    const f32x2 prx0v = {prx0, prx0}, pry0v = {pry0, pry0}, prz0v = {prz0, prz0};

    // k-side global row pointers (pre-scaled)
    const float* gX = posT + 4 * (size_t)N;    // -2x
    const float* gY = posT + 5 * (size_t)N;    // -2y
    const float* gZ = posT + 6 * (size_t)N;    // -2z
    const float* gR = posT + 3 * (size_t)N;    // r^2

    short8 bones;
    #pragma unroll
    for (int j = 0; j < 8; ++j) bones[j] = (ncol == 0) ? (short)0x3F80 : (short)0;

    floatx4 acc0 = {0.f,0.f,0.f,0.f}, acc1 = {0.f,0.f,0.f,0.f}, accc = {0.f,0.f,0.f,0.f};

    const int c32 = tid & 31, r8 = tid >> 5;
    for (int kb = 0; kb < KCHUNK; kb += BK) {
        const int kg = kcbase + kb;
        __syncthreads();
        #pragma unroll
        for (int rr = 0; rr < 4; ++rr) {
            const int r = r8 + rr * 8;
            #pragma unroll
            for (int cc = 0; cc < 2; ++cc)
                *(uint4*)&sY[r * YSTR + cc * 256 + c32 * 8] =
                    *(const uint4*)(y1t + (size_t)r * N + kg + cc * 256 + c32 * 8);
        }
        __syncthreads();

        #pragma unroll 4
        for (int kt = 0; kt < BK; kt += 32) {
            const int koff = kt + quad * 8;
            const int g = kg + koff;
            const f32x2x2 xA = LD2G(gX + g), xB = LD2G(gX + g + 4);
            const f32x2x2 yA = LD2G(gY + g), yB = LD2G(gY + g + 4);
            const f32x2x2 zA = LD2G(gZ + g), zB = LD2G(gZ + g + 4);
            const f32x2x2 rA = LD2G(gR + g), rB = LD2G(gR + g + 4);

            short8 af0;
            MASK8(af0, xA, xB, yA, yB, zA, zB, rA, rB, prx0v, pry0v, prz0v, thr0)

            const short8 b0 = *(const short8*)&sY[(ncol)      * YSTR + koff];
            const short8 b1 = *(const short8*)&sY[(16 + ncol) * YSTR + koff];

            acc0 = __builtin_amdgcn_mfma_f32_16x16x32_bf16(af0, b0, acc0, 0, 0, 0);
            acc1 = __builtin_amdgcn_mfma_f32_16x16x32_bf16(af0, b1, acc1, 0, 0, 0);
            accc = __builtin_amdgcn_mfma_f32_16x16x32_bf16(af0, bones, accc, 0, 0, 0);
        }
    }

    // C layout: col = ncol, row = quad*4 + r
    float* p1 = part1 + (size_t)blockIdx.y * N * 32;
    float* pc = pcnt  + (size_t)blockIdx.y * N;
    const int orow0 = rowbase + wv * 16 + quad * 4;
    #pragma unroll
    for (int r = 0; r < 4; ++r) {
        const int orow = orow0 + r;
        p1[(size_t)orow * 32 + ncol]      = acc0[r];
        p1[(size_t)orow * 32 + 16 + ncol] = acc1[r];
        if (ncol == 0) pc[orow] = accc[r];
    }
}

// ---------------- mlp2: 256 blocks x 32 rows, 8 threads/row, shfl reduce ----------------
__global__ __launch_bounds__(256) void k_mlp2(
    const float* __restrict__ W2,    // (32,8)
    const float* __restrict__ b2,    // (8,)
    char* __restrict__ ws)
{
    __shared__ float sW2[256], sb2[8], sCnt[32];
    __shared__ __hip_bfloat16 sT[8 * 40];
    const int tid = threadIdx.x;
    for (int i = tid; i < 256; i += THREADS) sW2[i] = W2[i];
    if (tid < 8) sb2[tid] = b2[tid];

    const int rl = tid >> 3;          // 0..31
    const int cs = tid & 7;           // 0..7
    const int base = blockIdx.x * 32;
    const int row  = base + rl;
    const float* part1 = (const float*)(ws + P1_OFF);
    const float* pcnt  = (const float*)(ws + PC_OFF);

    float4 s = make_float4(0.f, 0.f, 0.f, 0.f);
    #pragma unroll
    for (int kc = 0; kc < KCHUNKS; ++kc) {
        const float4 v = *(const float4*)(part1 + ((size_t)kc * N + row) * 32 + cs * 4);
        s.x += v.x; s.y += v.y; s.z += v.z; s.w += v.w;
    }
    if (cs == 0) {
        float cv = 0.f;
        #pragma unroll
        for (int kc = 0; kc < KCHUNKS; ++kc) cv += pcnt[(size_t)kc * N + row];
        sCnt[rl] = cv;
        ((float*)(ws + CNTT_OFF))[row] = cv;
    }
    __syncthreads();

    const float inv = 1.0f / (sCnt[rl] + 1e-6f);
    const float h0 = fmaxf(s.x * inv, 0.f), h1 = fmaxf(s.y * inv, 0.f),
                h2 = fmaxf(s.z * inv, 0.f), h3 = fmaxf(s.w * inv, 0.f);

    float o[8];
    const int c = cs * 4;
    #pragma unroll
    for (int j = 0; j < 8; ++j)
        o[j] = h0 * sW2[c * 8 + j] + h1 * sW2[(c + 1) * 8 + j]
             + h2 * sW2[(c + 2) * 8 + j] + h3 * sW2[(c + 3) * 8 + j];

    #pragma unroll
    for (int m = 1; m < 8; m <<= 1) {
        #pragma unroll
        for (int j = 0; j < 8; ++j) o[j] += __shfl_xor(o[j], m, 64);
    }

    if (cs == 0) {
        #pragma unroll
        for (int j = 0; j < 8; ++j)
            sT[j * 40 + rl] = __float2bfloat16(o[j] + sb2[j]);
    }
    __syncthreads();

    __hip_bfloat16* y2t = (__hip_bfloat16*)(ws + Y2T_OFF);
    if (tid < 32) {
        const int j = tid >> 2, part = tid & 3;
        *(uint4*)(y2t + (size_t)j * N + base + part * 8) = *(const uint4*)&sT[j * 40 + part * 8];
    }
}

// ---------------- agg2: 64-row blocks, grid (128,8), pos from global, BK=512 ----------------
__global__ __launch_bounds__(256, 4) void k_agg2(char* __restrict__ ws)
{
    __shared__ __hip_bfloat16 sY[9 * YSTR];   // rows 0-7 data, row 8 zeros (~9.4 KB)

    const float* posT = (const float*)(ws + POST_OFF);
    const __hip_bfloat16* y2t = (const __hip_bfloat16*)(ws + Y2T_OFF);
    float* part2 = (float*)(ws + P2_OFF);

    const int tid  = threadIdx.x;
    const int lane = tid & 63;
    const int wv   = tid >> 6;
    const int quad = lane >> 4;
    const int ncol = lane & 15;
    const int rowbase = blockIdx.x * 64;
    const int kcbase  = blockIdx.y * KCHUNK;

    // zero row 8 (read by lanes with ncol >= 8)
    for (int i = tid; i < 64; i += THREADS) {
        const uint4 z = {0u, 0u, 0u, 0u};
        *(uint4*)&sY[8 * YSTR + i * 8] = z;
    }

    const int m0 = rowbase + wv * 16 + ncol;
    const float prx0 = posT[m0], pry0 = posT[N + m0], prz0 = posT[2 * N + m0];
    const float thr0 = 6.25f - posT[3 * N + m0];

    const f32x2 prx0v = {prx0, prx0}, pry0v = {pry0, pry0}, prz0v = {prz0, prz0};

    const float* gX = posT + 4 * (size_t)N;
    const float* gY = posT + 5 * (size_t)N;
    const float* gZ = posT + 6 * (size_t)N;
    const float* gR = posT + 3 * (size_t)N;

    const int brow = (ncol < 8) ? ncol : 8;

    floatx4 acc0 = {0.f,0.f,0.f,0.f};

    const int c32 = tid & 31, r8 = tid >> 5;
    for (int kb = 0; kb < KCHUNK; kb += BK) {
        const int kg = kcbase + kb;
        __syncthreads();
        #pragma unroll
        for (int cc = 0; cc < 2; ++cc)
            *(uint4*)&sY[r8 * YSTR + cc * 256 + c32 * 8] =
                *(const uint4*)(y2t + (size_t)r8 * N + kg + cc * 256 + c32 * 8);
        __syncthreads();

        #pragma unroll 4
        for (int kt = 0; kt < BK; kt += 32) {
            const int koff = kt + quad * 8;
            const int g = kg + koff;
            const f32x2x2 xA = LD2G(gX + g), xB = LD2G(gX + g + 4);
            const f32x2x2 yA = LD2G(gY + g), yB = LD2G(gY + g + 4);
            const f32x2x2 zA = LD2G(gZ + g), zB = LD2G(gZ + g + 4);
            const f32x2x2 rA = LD2G(gR + g), rB = LD2G(gR + g + 4);

            short8 af0;
            MASK8(af0, xA, xB, yA, yB, zA, zB, rA, rB, prx0v, pry0v, prz0v, thr0)

            const short8 b0 = *(const short8*)&sY[brow * YSTR + koff];
            acc0 = __builtin_amdgcn_mfma_f32_16x16x32_bf16(af0, b0, acc0, 0, 0, 0);
        }
    }

    float* p2 = part2 + (size_t)blockIdx.y * N * 8;
    const int orow0 = rowbase + wv * 16 + quad * 4;
    #pragma unroll
    for (int r = 0; r < 4; ++r) {
        if (ncol < 8) {
            const int orow = orow0 + r;
            p2[(size_t)orow * 8 + ncol] = acc0[r];
        }
    }
}

// ---------------- out: 128 blocks x 64 rows, 4 chunk-partials/row, LDS reduce ----------------
__global__ __launch_bounds__(256) void k_out(char* __restrict__ ws, float* __restrict__ out)
{
    __shared__ float sP[4][64][8];    // 8 KB
    const int tid = threadIdx.x;
    const int rl = tid & 63, pp = tid >> 6;
    const int row = blockIdx.x * 64 + rl;
    const float* part2 = (const float*)(ws + P2_OFF);

    float s[8];
    #pragma unroll
    for (int j = 0; j < 8; ++j) s[j] = 0.f;
    #pragma unroll
    for (int t = 0; t < 2; ++t) {
        const int kc = pp * 2 + t;
        const float4* p4 = (const float4*)(part2 + ((size_t)kc * N + row) * 8);
        const float4 v0 = p4[0], v1 = p4[1];
        s[0] += v0.x; s[1] += v0.y; s[2] += v0.z; s[3] += v0.w;
        s[4] += v1.x; s[5] += v1.y; s[6] += v1.z; s[7] += v1.w;
    }
    #pragma unroll
    for (int j = 0; j < 8; ++j) sP[pp][rl][j] = s[j];
    __syncthreads();

    if (tid < 64) {
        const int r = blockIdx.x * 64 + tid;
        const float cv  = ((const float*)(ws + CNTT_OFF))[r];
        const float inv = 1.0f / (cv + 1e-6f);
        float t0[8];
        #pragma unroll
        for (int j = 0; j < 8; ++j)
            t0[j] = sP[0][tid][j] + sP[1][tid][j] + sP[2][tid][j] + sP[3][tid][j];
        float4* op = (float4*)(out + (size_t)r * 8);
        op[0] = make_float4(fmaxf(t0[0]*inv,0.f), fmaxf(t0[1]*inv,0.f),
                            fmaxf(t0[2]*inv,0.f), fmaxf(t0[3]*inv,0.f));
        op[1] = make_float4(fmaxf(t0[4]*inv,0.f), fmaxf(t0[5]*inv,0.f),
                            fmaxf(t0[6]*inv,0.f), fmaxf(t0[7]*inv,0.f));
    }
}

extern "C" void kernel_launch(void* const* d_in, const int* in_sizes, int n_in,
                              void* d_out, int out_size, void* d_ws, size_t ws_size,
                              hipStream_t stream) {
    (void)in_sizes; (void)n_in; (void)out_size; (void)ws_size;
    char* ws = (char*)d_ws;
    const float* lpf = (const float*)d_in[0];
    const float* B   = (const float*)d_in[1];
    const float* emb = (const float*)d_in[2];
    const float* W1  = (const float*)d_in[3];
    const float* b1  = (const float*)d_in[4];
    const float* W2  = (const float*)d_in[5];
    const float* b2  = (const float*)d_in[6];

    k_prep<<<N / 32, THREADS, 0, stream>>>(lpf, B, emb, W1, b1, ws);
    k_agg1<<<dim3(N / 64, KCHUNKS), THREADS, 0, stream>>>(ws);
    k_mlp2<<<N / 32, THREADS, 0, stream>>>(W2, b2, ws);
    k_agg2<<<dim3(N / 64, KCHUNKS), THREADS, 0, stream>>>(ws);
    k_out <<<N / 64, THREADS, 0, stream>>>(ws, (float*)d_out);
}

// Round 5
// 107.391 us; speedup vs baseline: 3.3354x; 1.3690x over previous
//
#include <hip/hip_runtime.h>
#include <hip/hip_bf16.h>

#define N 8192
#define THREADS 256
#define KCHUNKS 8
#define KCHUNK (N / KCHUNKS)   // 1024
#define BK 512
#define YSTR 520               // padded LDS stride (bf16 elements)
#define PSTR 520               // padded LDS stride (floats)

typedef __attribute__((ext_vector_type(8))) short short8;
typedef __attribute__((ext_vector_type(4))) float floatx4;
typedef __attribute__((ext_vector_type(2))) float f32x2;
typedef __attribute__((ext_vector_type(4))) unsigned int uint32x4;

struct f32x2x2 { f32x2 lo, hi; };

// ---- workspace byte offsets (total ~11.7 MB) ----
#define POST_OFF  0u           // float[8*N]: x,y,z,r2,-2x,-2y,-2z    262144
#define Y1T_OFF   262144u      // bf16[32*N]                           524288
#define Y2T_OFF   786432u      // bf16[8*N]                            131072
#define CNTT_OFF  917504u      // float[N]                              32768
#define PC_OFF    950272u      // float[8*N]                           262144
#define P1_OFF    1212416u     // float[8*N*32]                       8388608
#define P2_OFF    9601024u     // float[8*N*8]                        2097152

__device__ __forceinline__ f32x2 pk_fma(f32x2 a, f32x2 b, f32x2 c) {
    f32x2 d; asm("v_pk_fma_f32 %0, %1, %2, %3" : "=v"(d) : "v"(a), "v"(b), "v"(c)); return d;
}

#define LD2(P) __builtin_bit_cast(f32x2x2, *(const float4*)(P))

// k-side rows pre-scaled: X=-2x_k, Y=-2y_k, Z=-2z_k, R=r_k^2
// t = r_k^2 - 2*dot(p_m,p_k);  t < 6.25 - r_m^2  <=>  d^2 < 6.25
#define MASK2(XP, YP, ZP, RP, PRXV, PRYV, PRZV, THR, OUT) { \
    f32x2 _t = pk_fma((XP), (PRXV), (RP)); \
    _t = pk_fma((YP), (PRYV), _t); \
    _t = pk_fma((ZP), (PRZV), _t); \
    (OUT) = (_t.x < (THR) ? 0x3F80u : 0u) | (_t.y < (THR) ? 0x3F800000u : 0u); }

#define MASK8(OUT, XA, XB, YA, YB, ZA, ZB, RA, RB, PRXV, PRYV, PRZV, THR) { \
    uint32x4 _u; \
    MASK2(XA.lo, YA.lo, ZA.lo, RA.lo, PRXV, PRYV, PRZV, THR, _u[0]) \
    MASK2(XA.hi, YA.hi, ZA.hi, RA.hi, PRXV, PRYV, PRZV, THR, _u[1]) \
    MASK2(XB.lo, YB.lo, ZB.lo, RB.lo, PRXV, PRYV, PRZV, THR, _u[2]) \
    MASK2(XB.hi, YB.hi, ZB.hi, RB.hi, PRXV, PRYV, PRZV, THR, _u[3]) \
    (OUT) = __builtin_bit_cast(short8, _u); }

// ---------------- prep: 256 blocks x 32 rows, 8 threads/row ----------------
__global__ __launch_bounds__(256) void k_prep(
    const float* __restrict__ lpf,    // (N,4) float32
    const float* __restrict__ Bm,     // (3,16)
    const float* __restrict__ emb,    // (13,8)
    const float* __restrict__ W1,     // (40,32)
    const float* __restrict__ b1,     // (32,)
    char* __restrict__ ws)
{
    __shared__ float sB[48], sEmb[104], sW1[1280], sb1[32];
    __shared__ float xfs[32][41];
    __shared__ __hip_bfloat16 sT[32 * 36];

    const int tid = threadIdx.x;
    for (int i = tid; i < 48;   i += THREADS) sB[i]   = Bm[i];
    for (int i = tid; i < 104;  i += THREADS) sEmb[i] = emb[i];
    for (int i = tid; i < 1280; i += THREADS) sW1[i]  = W1[i];
    for (int i = tid; i < 32;   i += THREADS) sb1[i]  = b1[i];
    __syncthreads();

    const int row_local = tid >> 3;            // 0..31
    const int fslice    = tid & 7;             // 0..7
    const int base = blockIdx.x * 32;
    const int row  = base + row_local;

    const float4 lp = ((const float4*)lpf)[row];
    const float px = lp.x, py = lp.y, pz = lp.z;
    int fi = (int)lp.w;
    fi = fi < 0 ? 0 : (fi > 12 ? 12 : fi);
    const float r2 = px * px + py * py + pz * pz;
    float* posT = (float*)(ws + POST_OFF);
    if (fslice < 7) {
        const float v = (fslice == 0) ? px
                      : (fslice == 1) ? py
                      : (fslice == 2) ? pz
                      : (fslice == 3) ? r2
                      : (fslice == 4) ? -2.0f * px
                      : (fslice == 5) ? -2.0f * py
                      :                 -2.0f * pz;
        posT[(size_t)fslice * N + row] = v;
    }

    const float TWO_PI = 6.283185307179586f;
    #pragma unroll
    for (int t = 0; t < 2; ++t) {
        const int k = fslice * 2 + t;          // 0..15
        const float pr = (px * sB[k] + py * sB[16 + k] + pz * sB[32 + k]) * TWO_PI;
        xfs[row_local][k]      = sinf(pr);
        xfs[row_local][16 + k] = cosf(pr);
    }
    xfs[row_local][32 + fslice] = sEmb[fi * 8 + fslice];
    __syncthreads();

    float acc[4];
    #pragma unroll
    for (int j = 0; j < 4; ++j) acc[j] = sb1[fslice * 4 + j];
    #pragma unroll
    for (int f = 0; f < 40; ++f) {
        const float xv = xfs[row_local][f];
        #pragma unroll
        for (int j = 0; j < 4; ++j)
            acc[j] += xv * sW1[f * 32 + fslice * 4 + j];
    }
    #pragma unroll
    for (int j = 0; j < 4; ++j)
        sT[(fslice * 4 + j) * 36 + row_local] = __float2bfloat16(acc[j]);
    __syncthreads();

    __hip_bfloat16* y1t = (__hip_bfloat16*)(ws + Y1T_OFF);
    if (tid < 128) {
        const int feat = tid >> 2, chunk = tid & 3;
        *(uint4*)(y1t + (size_t)feat * N + base + chunk * 8) = *(const uint4*)&sT[feat * 36 + chunk * 8];
    }
}

// ---------------- agg1: partial sums(A @ y1) + cnt via MFMA, 128-row blocks, BK=512 ----------------
__global__ __launch_bounds__(256, 2) void k_agg1(char* __restrict__ ws)
{
    __shared__ __hip_bfloat16 sY[32 * YSTR];   // 33280 B
    __shared__ float sPos[4 * PSTR];           //  8320 B

    const float* posT = (const float*)(ws + POST_OFF);
    const __hip_bfloat16* y1t = (const __hip_bfloat16*)(ws + Y1T_OFF);
    float* part1 = (float*)(ws + P1_OFF);
    float* pcnt  = (float*)(ws + PC_OFF);

    const int tid  = threadIdx.x;
    const int lane = tid & 63;
    const int wv   = tid >> 6;        // wave 0..3
    const int quad = lane >> 4;       // 0..3
    const int ncol = lane & 15;
    const int rowbase = blockIdx.x * 128;
    const int kcbase  = blockIdx.y * KCHUNK;

    const int m0 = rowbase + wv * 32 + ncol;
    const int m1 = m0 + 16;
    const float prx0 = posT[m0], pry0 = posT[N + m0], prz0 = posT[2 * N + m0];
    const float thr0 = 6.25f - posT[3 * N + m0];
    const float prx1 = posT[m1], pry1 = posT[N + m1], prz1 = posT[2 * N + m1];
    const float thr1 = 6.25f - posT[3 * N + m1];

    const f32x2 prx0v = {prx0, prx0}, pry0v = {pry0, pry0}, prz0v = {prz0, prz0};
    const f32x2 prx1v = {prx1, prx1}, pry1v = {pry1, pry1}, prz1v = {prz1, prz1};

    short8 bones;
    #pragma unroll
    for (int j = 0; j < 8; ++j) bones[j] = (ncol == 0) ? (short)0x3F80 : (short)0;

    floatx4 acc[2][2], accc[2];
    #pragma unroll
    for (int t = 0; t < 2; ++t) {
        acc[t][0] = (floatx4){0.f,0.f,0.f,0.f};
        acc[t][1] = (floatx4){0.f,0.f,0.f,0.f};
        accc[t]   = (floatx4){0.f,0.f,0.f,0.f};
    }

    const int c32 = tid & 31, r8 = tid >> 5;
    for (int kb = 0; kb < KCHUNK; kb += BK) {
        const int kg = kcbase + kb;
        __syncthreads();
        #pragma unroll
        for (int rr = 0; rr < 4; ++rr) {
            const int r = r8 + rr * 8;
            #pragma unroll
            for (int cc = 0; cc < 2; ++cc)
                *(uint4*)&sY[r * YSTR + cc * 256 + c32 * 8] =
                    *(const uint4*)(y1t + (size_t)r * N + kg + cc * 256 + c32 * 8);
        }
        {   // stage k-side rows: -2x,-2y,-2z,r2  (posT rows 4,5,6,3)
            const int dim = tid >> 6, i = tid & 63;
            const int srow = (dim == 3) ? 3 : 4 + dim;
            #pragma unroll
            for (int cc = 0; cc < 2; ++cc)
                *(float4*)&sPos[dim * PSTR + cc * 256 + i * 4] =
                    *(const float4*)(posT + (size_t)srow * N + kg + cc * 256 + i * 4);
        }
        __syncthreads();

        #pragma unroll 4
        for (int kt = 0; kt < BK; kt += 32) {
            const int koff = kt + quad * 8;
            const f32x2x2 xA = LD2(&sPos[koff]),            xB = LD2(&sPos[koff + 4]);
            const f32x2x2 yA = LD2(&sPos[PSTR + koff]),     yB = LD2(&sPos[PSTR + koff + 4]);
            const f32x2x2 zA = LD2(&sPos[2 * PSTR + koff]), zB = LD2(&sPos[2 * PSTR + koff + 4]);
            const f32x2x2 rA = LD2(&sPos[3 * PSTR + koff]), rB = LD2(&sPos[3 * PSTR + koff + 4]);

            short8 af0, af1;
            MASK8(af0, xA, xB, yA, yB, zA, zB, rA, rB, prx0v, pry0v, prz0v, thr0)
            MASK8(af1, xA, xB, yA, yB, zA, zB, rA, rB, prx1v, pry1v, prz1v, thr1)

            const short8 b0 = *(const short8*)&sY[(ncol)      * YSTR + koff];
            const short8 b1 = *(const short8*)&sY[(16 + ncol) * YSTR + koff];

            acc[0][0] = __builtin_amdgcn_mfma_f32_16x16x32_bf16(af0, b0, acc[0][0], 0, 0, 0);
            acc[0][1] = __builtin_amdgcn_mfma_f32_16x16x32_bf16(af0, b1, acc[0][1], 0, 0, 0);
            accc[0]   = __builtin_amdgcn_mfma_f32_16x16x32_bf16(af0, bones, accc[0], 0, 0, 0);
            acc[1][0] = __builtin_amdgcn_mfma_f32_16x16x32_bf16(af1, b0, acc[1][0], 0, 0, 0);
            acc[1][1] = __builtin_amdgcn_mfma_f32_16x16x32_bf16(af1, b1, acc[1][1], 0, 0, 0);
            accc[1]   = __builtin_amdgcn_mfma_f32_16x16x32_bf16(af1, bones, accc[1], 0, 0, 0);
        }
    }

    // C layout: col = ncol, row = quad*4 + r
    float* p1 = part1 + (size_t)blockIdx.y * N * 32;
    float* pc = pcnt  + (size_t)blockIdx.y * N;
    #pragma unroll
    for (int t = 0; t < 2; ++t) {
        const int orow0 = rowbase + wv * 32 + t * 16 + quad * 4;
        #pragma unroll
        for (int r = 0; r < 4; ++r) {
            const int orow = orow0 + r;
            p1[(size_t)orow * 32 + ncol]      = acc[t][0][r];
            p1[(size_t)orow * 32 + 16 + ncol] = acc[t][1][r];
            if (ncol == 0) pc[orow] = accc[t][r];
        }
    }
}

// ---------------- mlp2: 256 blocks x 32 rows, 8 threads/row, shfl reduce ----------------
__global__ __launch_bounds__(256) void k_mlp2(
    const float* __restrict__ W2,    // (32,8)
    const float* __restrict__ b2,    // (8,)
    char* __restrict__ ws)
{
    __shared__ float sW2[256], sb2[8], sCnt[32];
    __shared__ __hip_bfloat16 sT[8 * 40];
    const int tid = threadIdx.x;
    for (int i = tid; i < 256; i += THREADS) sW2[i] = W2[i];
    if (tid < 8) sb2[tid] = b2[tid];

    const int rl = tid >> 3;          // 0..31
    const int cs = tid & 7;           // 0..7
    const int base = blockIdx.x * 32;
    const int row  = base + rl;
    const float* part1 = (const float*)(ws + P1_OFF);
    const float* pcnt  = (const float*)(ws + PC_OFF);

    float4 s = make_float4(0.f, 0.f, 0.f, 0.f);
    #pragma unroll
    for (int kc = 0; kc < KCHUNKS; ++kc) {
        const float4 v = *(const float4*)(part1 + ((size_t)kc * N + row) * 32 + cs * 4);
        s.x += v.x; s.y += v.y; s.z += v.z; s.w += v.w;
    }
    if (cs == 0) {
        float cv = 0.f;
        #pragma unroll
        for (int kc = 0; kc < KCHUNKS; ++kc) cv += pcnt[(size_t)kc * N + row];
        sCnt[rl] = cv;
        ((float*)(ws + CNTT_OFF))[row] = cv;
    }
    __syncthreads();

    const float inv = 1.0f / (sCnt[rl] + 1e-6f);
    const float h0 = fmaxf(s.x * inv, 0.f), h1 = fmaxf(s.y * inv, 0.f),
                h2 = fmaxf(s.z * inv, 0.f), h3 = fmaxf(s.w * inv, 0.f);

    float o[8];
    const int c = cs * 4;
    #pragma unroll
    for (int j = 0; j < 8; ++j)
        o[j] = h0 * sW2[c * 8 + j] + h1 * sW2[(c + 1) * 8 + j]
             + h2 * sW2[(c + 2) * 8 + j] + h3 * sW2[(c + 3) * 8 + j];

    #pragma unroll
    for (int m = 1; m < 8; m <<= 1) {
        #pragma unroll
        for (int j = 0; j < 8; ++j) o[j] += __shfl_xor(o[j], m, 64);
    }

    if (cs == 0) {
        #pragma unroll
        for (int j = 0; j < 8; ++j)
            sT[j * 40 + rl] = __float2bfloat16(o[j] + sb2[j]);
    }
    __syncthreads();

    __hip_bfloat16* y2t = (__hip_bfloat16*)(ws + Y2T_OFF);
    if (tid < 32) {
        const int j = tid >> 2, part = tid & 3;
        *(uint4*)(y2t + (size_t)j * N + base + part * 8) = *(const uint4*)&sT[j * 40 + part * 8];
    }
}

// ---------------- agg2: partial sums(A @ y2) via MFMA, 128-row blocks, BK=512 ----------------
__global__ __launch_bounds__(256, 2) void k_agg2(char* __restrict__ ws)
{
    __shared__ __hip_bfloat16 sY[9 * YSTR];   // rows 0-7 data, row 8 zeros
    __shared__ float sPos[4 * PSTR];

    const float* posT = (const float*)(ws + POST_OFF);
    const __hip_bfloat16* y2t = (const __hip_bfloat16*)(ws + Y2T_OFF);
    float* part2 = (float*)(ws + P2_OFF);

    const int tid  = threadIdx.x;
    const int lane = tid & 63;
    const int wv   = tid >> 6;
    const int quad = lane >> 4;
    const int ncol = lane & 15;
    const int rowbase = blockIdx.x * 128;
    const int kcbase  = blockIdx.y * KCHUNK;

    // zero row 8 (read by lanes with ncol >= 8)
    for (int i = tid; i < 64; i += THREADS) {
        const uint4 z = {0u, 0u, 0u, 0u};
        *(uint4*)&sY[8 * YSTR + i * 8] = z;
    }

    const int m0 = rowbase + wv * 32 + ncol;
    const int m1 = m0 + 16;
    const float prx0 = posT[m0], pry0 = posT[N + m0], prz0 = posT[2 * N + m0];
    const float thr0 = 6.25f - posT[3 * N + m0];
    const float prx1 = posT[m1], pry1 = posT[N + m1], prz1 = posT[2 * N + m1];
    const float thr1 = 6.25f - posT[3 * N + m1];

    const f32x2 prx0v = {prx0, prx0}, pry0v = {pry0, pry0}, prz0v = {prz0, prz0};
    const f32x2 prx1v = {prx1, prx1}, pry1v = {pry1, pry1}, prz1v = {prz1, prz1};

    const int brow = (ncol < 8) ? ncol : 8;

    floatx4 acc[2];
    acc[0] = (floatx4){0.f,0.f,0.f,0.f};
    acc[1] = (floatx4){0.f,0.f,0.f,0.f};

    const int c32 = tid & 31, r8 = tid >> 5;
    for (int kb = 0; kb < KCHUNK; kb += BK) {
        const int kg = kcbase + kb;
        __syncthreads();
        #pragma unroll
        for (int cc = 0; cc < 2; ++cc)
            *(uint4*)&sY[r8 * YSTR + cc * 256 + c32 * 8] =
                *(const uint4*)(y2t + (size_t)r8 * N + kg + cc * 256 + c32 * 8);
        {
            const int dim = tid >> 6, i = tid & 63;
            const int srow = (dim == 3) ? 3 : 4 + dim;
            #pragma unroll
            for (int cc = 0; cc < 2; ++cc)
                *(float4*)&sPos[dim * PSTR + cc * 256 + i * 4] =
                    *(const float4*)(posT + (size_t)srow * N + kg + cc * 256 + i * 4);
        }
        __syncthreads();

        #pragma unroll 4
        for (int kt = 0; kt < BK; kt += 32) {
            const int koff = kt + quad * 8;
            const f32x2x2 xA = LD2(&sPos[koff]),            xB = LD2(&sPos[koff + 4]);
            const f32x2x2 yA = LD2(&sPos[PSTR + koff]),     yB = LD2(&sPos[PSTR + koff + 4]);
            const f32x2x2 zA = LD2(&sPos[2 * PSTR + koff]), zB = LD2(&sPos[2 * PSTR + koff + 4]);
            const f32x2x2 rA = LD2(&sPos[3 * PSTR + koff]), rB = LD2(&sPos[3 * PSTR + koff + 4]);

            short8 af0, af1;
            MASK8(af0, xA, xB, yA, yB, zA, zB, rA, rB, prx0v, pry0v, prz0v, thr0)
            MASK8(af1, xA, xB, yA, yB, zA, zB, rA, rB, prx1v, pry1v, prz1v, thr1)

            const short8 b0 = *(const short8*)&sY[brow * YSTR + koff];
            acc[0] = __builtin_amdgcn_mfma_f32_16x16x32_bf16(af0, b0, acc[0], 0, 0, 0);
            acc[1] = __builtin_amdgcn_mfma_f32_16x16x32_bf16(af1, b0, acc[1], 0, 0, 0);
        }
    }

    float* p2 = part2 + (size_t)blockIdx.y * N * 8;
    #pragma unroll
    for (int t = 0; t < 2; ++t) {
        const int orow0 = rowbase + wv * 32 + t * 16 + quad * 4;
        #pragma unroll
        for (int r = 0; r < 4; ++r) {
            if (ncol < 8) {
                const int orow = orow0 + r;
                p2[(size_t)orow * 8 + ncol] = acc[t][r];
            }
        }
    }
}

// ---------------- out: 128 blocks x 64 rows, 4 chunk-partials/row, LDS reduce ----------------
__global__ __launch_bounds__(256) void k_out(char* __restrict__ ws, float* __restrict__ out)
{
    __shared__ float sP[4][64][8];    // 8 KB
    const int tid = threadIdx.x;
    const int rl = tid & 63, pp = tid >> 6;
    const int row = blockIdx.x * 64 + rl;
    const float* part2 = (const float*)(ws + P2_OFF);

    float s[8];
    #pragma unroll
    for (int j = 0; j < 8; ++j) s[j] = 0.f;
    #pragma unroll
    for (int t = 0; t < 2; ++t) {
        const int kc = pp * 2 + t;
        const float4* p4 = (const float4*)(part2 + ((size_t)kc * N + row) * 8);
        const float4 v0 = p4[0], v1 = p4[1];
        s[0] += v0.x; s[1] += v0.y; s[2] += v0.z; s[3] += v0.w;
        s[4] += v1.x; s[5] += v1.y; s[6] += v1.z; s[7] += v1.w;
    }
    #pragma unroll
    for (int j = 0; j < 8; ++j) sP[pp][rl][j] = s[j];
    __syncthreads();

    if (tid < 64) {
        const int r = blockIdx.x * 64 + tid;
        const float cv  = ((const float*)(ws + CNTT_OFF))[r];
        const float inv = 1.0f / (cv + 1e-6f);
        float t0[8];
        #pragma unroll
        for (int j = 0; j < 8; ++j)
            t0[j] = sP[0][tid][j] + sP[1][tid][j] + sP[2][tid][j] + sP[3][tid][j];
        float4* op = (float4*)(out + (size_t)r * 8);
        op[0] = make_float4(fmaxf(t0[0]*inv,0.f), fmaxf(t0[1]*inv,0.f),
                            fmaxf(t0[2]*inv,0.f), fmaxf(t0[3]*inv,0.f));
        op[1] = make_float4(fmaxf(t0[4]*inv,0.f), fmaxf(t0[5]*inv,0.f),
                            fmaxf(t0[6]*inv,0.f), fmaxf(t0[7]*inv,0.f));
    }
}

extern "C" void kernel_launch(void* const* d_in, const int* in_sizes, int n_in,
                              void* d_out, int out_size, void* d_ws, size_t ws_size,
                              hipStream_t stream) {
    (void)in_sizes; (void)n_in; (void)out_size; (void)ws_size;
    char* ws = (char*)d_ws;
    const float* lpf = (const float*)d_in[0];
    const float* B   = (const float*)d_in[1];
    const float* emb = (const float*)d_in[2];
    const float* W1  = (const float*)d_in[3];
    const float* b1  = (const float*)d_in[4];
    const float* W2  = (const float*)d_in[5];
    const float* b2  = (const float*)d_in[6];

    k_prep<<<N / 32, THREADS, 0, stream>>>(lpf, B, emb, W1, b1, ws);
    k_agg1<<<dim3(N / 128, KCHUNKS), THREADS, 0, stream>>>(ws);
    k_mlp2<<<N / 32, THREADS, 0, stream>>>(W2, b2, ws);
    k_agg2<<<dim3(N / 128, KCHUNKS), THREADS, 0, stream>>>(ws);
    k_out <<<N / 64, THREADS, 0, stream>>>(ws, (float*)d_out);
}